// Round 16
// baseline (51.112 us; speedup 1.0000x reference)
//
#include <hip/hip_runtime.h>

#define N_SUBJ 4096
#define N_STEPS 2048
#define N_DOSES 8

#define DT   0.24609375f          // 504/2048, exact

__device__ __forceinline__ float softplusf(float x) {
    return fmaxf(x, 0.0f) + log1pf(expf(-fabsf(x)));
}

__device__ __forceinline__ void mm3(float* C, const float* A, const float* B) {
#pragma unroll
    for (int i = 0; i < 3; ++i)
#pragma unroll
        for (int j = 0; j < 3; ++j)
            C[3 * i + j] = A[3 * i] * B[j] + A[3 * i + 1] * B[3 + j] + A[3 * i + 2] * B[6 + j];
}

// DPP helper: shifted/broadcast value; lanes excluded by row_mask (or with an
// invalid source, via bound_ctrl) return 0 -> their fmaf contribution is zero.
#define DPPF(v, ctrl, rmask) __int_as_float(__builtin_amdgcn_update_dpp( \
        0, __float_as_int(v), (ctrl), (rmask), 0xf, true))

// wave-uniform value -> SGPR
__device__ __forceinline__ float rfl(float x) {
    return __int_as_float(__builtin_amdgcn_readfirstlane(__float_as_int(x)));
}

// Two waves per subject. Role 0 stores rounds 0..23; role 1 redundantly
// re-runs rounds 0..23 light (no store/output-matvec) to build the R carry,
// then stores rounds 24..31. No inter-wave communication; stored arithmetic
// is bit-identical to the single-wave version.
__global__ __launch_bounds__(256, 8) void pkpd_split_kernel(
    const float* __restrict__ cov,       // (N,2)
    const float* __restrict__ dose_int,  // (N,)
    const float* __restrict__ Wm,        // (3,9)
    const float* __restrict__ bvec,      // (9,)
    const float* __restrict__ dose_amt,  // (N,8)
    float* __restrict__ out)             // (N, N_STEPS+1, 4)
{
    const int c = threadIdx.x & 63;
    const int g = blockIdx.x * 4 + (threadIdx.x >> 6);
    const int subj = g >> 1;
    const int role = g & 1;

    // ---- parameter network ----
    const float f0 = cov[2 * subj] * 0.01f;
    const float f1 = cov[2 * subj + 1];
    const float f2 = dose_int[subj];

    float P[9];
#pragma unroll
    for (int p = 0; p < 9; ++p) {
        float z = f0 * Wm[p] + f1 * Wm[9 + p] + f2 * Wm[18 + p] + bvec[p];
        P[p] = softplusf(z) + 0.01f;
    }
    const float Ka = P[0], CL = P[1], Vc = P[2], Q_ = P[3], Vp = P[4];
    const float Kin = P[5], Kout = P[6], Imax = P[7], IC50 = P[8];

    const float k10 = CL / Vc, k12 = Q_ / Vc, k21 = Q_ / Vp;
    const float IC50p = IC50 + 1e-6f;

    // ---- R recurrence constants: R' = alpha*R + beta ----
    const float x = DT * Kout;
    const float x2 = x * x;
    const float alpha = 1.0f - x + 0.5f * x2 - (1.0f / 6.0f) * x2 * x + (1.0f / 24.0f) * x2 * x2;
    const float a = 0.5f * x;
    const float g1 = 1.0f - 2.0f * a + 2.0f * a * a - 2.0f * a * a * a;
    const float g2 = 2.0f - 2.0f * a + 2.0f * a * a;
    const float g3 = 2.0f - 2.0f * a;
    const float s0 = DT * Kin * (1.0f / 6.0f);
    const float w1 = s0 * g1, w2 = s0 * g2, w3 = s0 * g3, w4 = s0;
    const float beta0v = w1 + w2 + w3 + w4;

    // ---- stage matrices: S2 = I+Am/2, S3 = I+Am*S2/2, S4 = I+Am*S3 ----
    float Am[9] = { -DT * Ka, 0.0f, 0.0f,
                     DT * Ka, -DT * (k10 + k12), DT * k21,
                     0.0f, DT * k12, -DT * k21 };
    float S2[9], S3[9], S4[9], G[9], Phi[9];
#pragma unroll
    for (int e = 0; e < 9; ++e) S2[e] = 0.5f * Am[e];
    S2[0] += 1.0f; S2[4] += 1.0f; S2[8] += 1.0f;
    mm3(S3, Am, S2);
#pragma unroll
    for (int e = 0; e < 9; ++e) S3[e] = 0.5f * S3[e];
    S3[0] += 1.0f; S3[4] += 1.0f; S3[8] += 1.0f;
    mm3(S4, Am, S3);
    S4[0] += 1.0f; S4[4] += 1.0f; S4[8] += 1.0f;
#pragma unroll
    for (int e = 0; e < 9; ++e) G[e] = 2.0f * (S2[e] + S3[e]) + S4[e];
    G[0] += 1.0f; G[4] += 1.0f; G[8] += 1.0f;
    mm3(Phi, Am, G);
#pragma unroll
    for (int e = 0; e < 9; ++e) Phi[e] *= (1.0f / 6.0f);
    Phi[0] += 1.0f; Phi[4] += 1.0f; Phi[8] += 1.0f;

    // ---- v = Phi^c * e1 (per-lane) and F64 = Phi^64 (wave-uniform) ----
    float Pc[9], Tm[9];
#pragma unroll
    for (int e = 0; e < 9; ++e) Pc[e] = Phi[e];
    float v0 = 1.0f, v1 = 0.0f, v2 = 0.0f;
    if (c & 1) { v0 = Pc[0]; v1 = Pc[3]; v2 = Pc[6]; }
#pragma unroll
    for (int bb = 1; bb <= 5; ++bb) {
        mm3(Tm, Pc, Pc);
#pragma unroll
        for (int e = 0; e < 9; ++e) Pc[e] = Tm[e];           // Phi^(2^bb)
        float tv0 = Pc[0] * v0 + Pc[1] * v1 + Pc[2] * v2;
        float tv1 = Pc[3] * v0 + Pc[4] * v1 + Pc[5] * v2;
        float tv2 = Pc[6] * v0 + Pc[7] * v1 + Pc[8] * v2;
        const bool bit = (c >> bb) & 1;
        v0 = bit ? tv0 : v0; v1 = bit ? tv1 : v1; v2 = bit ? tv2 : v2;
    }
    mm3(Tm, Pc, Pc);                                         // Phi^64

    // ---- hoist wave-uniform constants to SGPRs ----
    float sPhi[9], sF64[9], sU[9];
#pragma unroll
    for (int e = 0; e < 9; ++e) {
        sPhi[e] = rfl(Phi[e]);
        sF64[e] = rfl(Tm[e]);
    }
    sU[0] = rfl(S2[3]); sU[1] = rfl(S2[4]); sU[2] = rfl(S2[5]);
    sU[3] = rfl(S3[3]); sU[4] = rfl(S3[4]); sU[5] = rfl(S3[5]);
    sU[6] = rfl(S4[3]); sU[7] = rfl(S4[4]); sU[8] = rfl(S4[5]);
    const float sD    = rfl(IC50p * Vc);          // denom scaled by Vc
    const float sWW1  = rfl(w1 * Imax);
    const float sWW2  = rfl(w2 * Imax);
    const float sWW3  = rfl(w3 * Imax);
    const float sWW4  = rfl(w4 * Imax);
    const float sB0   = rfl(beta0v);

    // scan weights (wave-uniform -> SGPR; fmac src0 may be SGPR)
    const float a1v = alpha, a2v = a1v * a1v, a4v = a2v * a2v;
    const float a8v = a4v * a4v, a16v = a8v * a8v, a32v = a16v * a16v;
    const float sA1 = rfl(a1v), sA2 = rfl(a2v), sA4 = rfl(a4v), sA8 = rfl(a8v);

    // per-lane weights (must be VGPR)
    float pca = a1v;                // alpha^(c+1)
    pca *= (c & 1)  ? a1v  : 1.0f;
    pca *= (c & 2)  ? a2v  : 1.0f;
    pca *= (c & 4)  ? a4v  : 1.0f;
    pca *= (c & 8)  ? a8v  : 1.0f;
    pca *= (c & 16) ? a16v : 1.0f;
    pca *= (c & 32) ? a32v : 1.0f;
    float w5 = a1v;                 // alpha^((c&15)+1), bridge rows 1&3
    w5 *= (c & 1) ? a1v : 1.0f;
    w5 *= (c & 2) ? a2v : 1.0f;
    w5 *= (c & 4) ? a4v : 1.0f;
    w5 *= (c & 8) ? a8v : 1.0f;
    float w6 = w5 * ((c & 16) ? a16v : 1.0f);   // alpha^((c&31)+1), rows 2&3

    // ---- initial state: x = dose0 * Phi^c e1;  R carry = 16 ----
    const float dose0 = dose_amt[subj * N_DOSES + 0];
    float x0 = dose0 * v0, x1d = dose0 * v1, x2d = dose0 * v2;
    float Rc = 16.0f;

    float4* orow = (float4*)out + (size_t)subj * (N_STEPS + 1);
    if (role == 0 && c == 0) orow[0] = make_float4(0.0f, 0.0f, 0.0f, 16.0f);
    float4* op = orow + 1 + c;

    // beta(x): single-rcp form
#define BETA_FROM_X(bout)                                                  \
    do {                                                                   \
        float s1_ = x1d;                                                   \
        float s2_ = sU[0] * x0 + sU[1] * x1d + sU[2] * x2d;                \
        float s3_ = sU[3] * x0 + sU[4] * x1d + sU[5] * x2d;                \
        float s4_ = sU[6] * x0 + sU[7] * x1d + sU[8] * x2d;                \
        float d1_ = sD + s1_, d2_ = sD + s2_;                              \
        float d3_ = sD + s3_, d4_ = sD + s4_;                              \
        float n12_ = fmaf(sWW1 * s1_, d2_, (sWW2 * s2_) * d1_);            \
        float n34_ = fmaf(sWW3 * s3_, d4_, (sWW4 * s4_) * d3_);            \
        float d12_ = d1_ * d2_, d34_ = d3_ * d4_;                          \
        float num_ = fmaf(n12_, d34_, n34_ * d12_);                        \
        float rcp_ = __builtin_amdgcn_rcpf(d12_ * d34_);                   \
        bout = sB0 - num_ * rcp_;                                          \
    } while (0)

    // One 64-step round. FULL: also compute output state + store.
    // Order: xn from old x; scan on bta(old x); advance x; next beta; store.
#define ROUND(SEG, J, FULL)                                                \
    do {                                                                   \
        float xn0, xn1, xn2;                                               \
        if (FULL) {                                                        \
            xn0 = sPhi[0] * x0 + sPhi[1] * x1d + sPhi[2] * x2d;            \
            xn1 = sPhi[3] * x0 + sPhi[4] * x1d + sPhi[5] * x2d;            \
            xn2 = sPhi[6] * x0 + sPhi[7] * x1d + sPhi[8] * x2d;            \
        }                                                                  \
        float I = bta;                                                     \
        I = fmaf(sA1, DPPF(I, 0x111, 0xf), I);   /* row_shr:1  */          \
        I = fmaf(sA2, DPPF(I, 0x112, 0xf), I);   /* row_shr:2  */          \
        I = fmaf(sA4, DPPF(I, 0x114, 0xf), I);   /* row_shr:4  */          \
        I = fmaf(sA8, DPPF(I, 0x118, 0xf), I);   /* row_shr:8  */          \
        I = fmaf(w5, DPPF(I, 0x142, 0xa), I);    /* bcast15 -> rows 1,3 */ \
        I = fmaf(w6, DPPF(I, 0x143, 0xc), I);    /* bcast31 -> rows 2,3 */ \
        float nx0 = sF64[0] * x0 + sF64[1] * x1d + sF64[2] * x2d;          \
        float nx1 = sF64[3] * x0 + sF64[4] * x1d + sF64[5] * x2d;          \
        float nx2 = sF64[6] * x0 + sF64[7] * x1d + sF64[8] * x2d;          \
        if ((J) == 3) {                                                    \
            nx0 = fmaf(dnext, v0, nx0);                                    \
            nx1 = fmaf(dnext, v1, nx1);                                    \
            nx2 = fmaf(dnext, v2, nx2);                                    \
        }                                                                  \
        x0 = nx0; x1d = nx1; x2d = nx2;                                    \
        BETA_FROM_X(bta);                                                  \
        float Rout = fmaf(pca, Rc, I);                                     \
        if (FULL) op[((SEG) * 4 + (J)) * 64] = make_float4(xn0, xn1, xn2, Rout); \
        Rc = __int_as_float(__builtin_amdgcn_readlane(__float_as_int(Rout), 63)); \
    } while (0)

    float bta;
    BETA_FROM_X(bta);

    if (role == 0) {
        // rounds 0..23, all stored
#pragma unroll 1
        for (int seg = 0; seg < 6; ++seg) {
            const float dnext = dose_amt[subj * N_DOSES + seg + 1];
            ROUND(seg, 0, true); ROUND(seg, 1, true);
            ROUND(seg, 2, true); ROUND(seg, 3, true);
        }
    } else {
        // rounds 0..23 light (carry only), 24..31 stored
#pragma unroll 1
        for (int seg = 0; seg < 6; ++seg) {
            const float dnext = dose_amt[subj * N_DOSES + seg + 1];
            ROUND(seg, 0, false); ROUND(seg, 1, false);
            ROUND(seg, 2, false); ROUND(seg, 3, false);
        }
#pragma unroll 1
        for (int seg = 6; seg < 8; ++seg) {
            const float dnext = (seg < 7) ? dose_amt[subj * N_DOSES + seg + 1] : 0.0f;
            ROUND(seg, 0, true); ROUND(seg, 1, true);
            ROUND(seg, 2, true); ROUND(seg, 3, true);
        }
    }
#undef ROUND
#undef BETA_FROM_X
}

extern "C" void kernel_launch(void* const* d_in, const int* in_sizes, int n_in,
                              void* d_out, int out_size, void* d_ws, size_t ws_size,
                              hipStream_t stream) {
    const float* cov      = (const float*)d_in[0];
    const float* dose_int = (const float*)d_in[1];
    const float* Wm       = (const float*)d_in[2];
    const float* bvec     = (const float*)d_in[3];
    const float* dose_amt = (const float*)d_in[4];
    float* out = (float*)d_out;

    pkpd_split_kernel<<<N_SUBJ * 2 / 4, 256, 0, stream>>>(cov, dose_int, Wm, bvec, dose_amt, out);
}

// Round 19
// 33.643 us; speedup vs baseline: 1.5193x; 1.5193x over previous
//
#include <hip/hip_runtime.h>

#define N_SUBJ 4096
#define N_STEPS 2048
#define N_DOSES 8

#define DT   0.24609375f          // 504/2048, exact

__device__ __forceinline__ float softplusf(float x) {
    return fmaxf(x, 0.0f) + log1pf(expf(-fabsf(x)));
}

__device__ __forceinline__ void mm3(float* C, const float* A, const float* B) {
#pragma unroll
    for (int i = 0; i < 3; ++i)
#pragma unroll
        for (int j = 0; j < 3; ++j)
            C[3 * i + j] = A[3 * i] * B[j] + A[3 * i + 1] * B[3 + j] + A[3 * i + 2] * B[6 + j];
}

// DPP helper: shifted/broadcast value; lanes excluded by row_mask (or with an
// invalid source, via bound_ctrl) return 0 -> their fmaf contribution is zero.
#define DPPF(v, ctrl, rmask) __int_as_float(__builtin_amdgcn_update_dpp( \
        0, __float_as_int(v), (ctrl), (rmask), 0xf, true))

// wave-uniform value -> SGPR
__device__ __forceinline__ float rfl(float x) {
    return __int_as_float(__builtin_amdgcn_readfirstlane(__float_as_int(x)));
}

// Lane c owns output indices {64k + c} (state AFTER 64k+c steps) and stores
// its carried state x directly -- no per-round output matvec. R at index
// 64k+c uses the exclusive weighted scan E = (I - beta)/alpha.
__global__ __launch_bounds__(256, 4) void pkpd_tint_kernel(
    const float* __restrict__ cov,       // (N,2)
    const float* __restrict__ dose_int,  // (N,)
    const float* __restrict__ Wm,        // (3,9)
    const float* __restrict__ bvec,      // (9,)
    const float* __restrict__ dose_amt,  // (N,8)
    float* __restrict__ out)             // (N, N_STEPS+1, 4)
{
    const int c = threadIdx.x & 63;
    const int subj = blockIdx.x * 4 + (threadIdx.x >> 6);

    // ---- parameter network ----
    const float f0 = cov[2 * subj] * 0.01f;
    const float f1 = cov[2 * subj + 1];
    const float f2 = dose_int[subj];

    float P[9];
#pragma unroll
    for (int p = 0; p < 9; ++p) {
        float z = f0 * Wm[p] + f1 * Wm[9 + p] + f2 * Wm[18 + p] + bvec[p];
        P[p] = softplusf(z) + 0.01f;
    }
    const float Ka = P[0], CL = P[1], Vc = P[2], Q_ = P[3], Vp = P[4];
    const float Kin = P[5], Kout = P[6], Imax = P[7], IC50 = P[8];

    const float k10 = CL / Vc, k12 = Q_ / Vc, k21 = Q_ / Vp;
    const float IC50p = IC50 + 1e-6f;

    // ---- R recurrence constants: R' = alpha*R + beta ----
    const float x = DT * Kout;
    const float x2 = x * x;
    const float alpha = 1.0f - x + 0.5f * x2 - (1.0f / 6.0f) * x2 * x + (1.0f / 24.0f) * x2 * x2;
    const float a = 0.5f * x;
    const float g1 = 1.0f - 2.0f * a + 2.0f * a * a - 2.0f * a * a * a;
    const float g2 = 2.0f - 2.0f * a + 2.0f * a * a;
    const float g3 = 2.0f - 2.0f * a;
    const float s0 = DT * Kin * (1.0f / 6.0f);
    const float w1 = s0 * g1, w2 = s0 * g2, w3 = s0 * g3, w4 = s0;
    const float beta0v = w1 + w2 + w3 + w4;

    // ---- stage matrices: S2 = I+Am/2, S3 = I+Am*S2/2, S4 = I+Am*S3 ----
    float Am[9] = { -DT * Ka, 0.0f, 0.0f,
                     DT * Ka, -DT * (k10 + k12), DT * k21,
                     0.0f, DT * k12, -DT * k21 };
    float S2[9], S3[9], S4[9], G[9], Phi[9];
#pragma unroll
    for (int e = 0; e < 9; ++e) S2[e] = 0.5f * Am[e];
    S2[0] += 1.0f; S2[4] += 1.0f; S2[8] += 1.0f;
    mm3(S3, Am, S2);
#pragma unroll
    for (int e = 0; e < 9; ++e) S3[e] = 0.5f * S3[e];
    S3[0] += 1.0f; S3[4] += 1.0f; S3[8] += 1.0f;
    mm3(S4, Am, S3);
    S4[0] += 1.0f; S4[4] += 1.0f; S4[8] += 1.0f;
#pragma unroll
    for (int e = 0; e < 9; ++e) G[e] = 2.0f * (S2[e] + S3[e]) + S4[e];
    G[0] += 1.0f; G[4] += 1.0f; G[8] += 1.0f;
    mm3(Phi, Am, G);
#pragma unroll
    for (int e = 0; e < 9; ++e) Phi[e] *= (1.0f / 6.0f);
    Phi[0] += 1.0f; Phi[4] += 1.0f; Phi[8] += 1.0f;

    // ---- v = Phi^c * e1 (per-lane) and F64 = Phi^64 (wave-uniform) ----
    float Pc[9], Tm[9];
#pragma unroll
    for (int e = 0; e < 9; ++e) Pc[e] = Phi[e];
    float v0 = 1.0f, v1 = 0.0f, v2 = 0.0f;
    if (c & 1) { v0 = Pc[0]; v1 = Pc[3]; v2 = Pc[6]; }
#pragma unroll
    for (int bb = 1; bb <= 5; ++bb) {
        mm3(Tm, Pc, Pc);
#pragma unroll
        for (int e = 0; e < 9; ++e) Pc[e] = Tm[e];           // Phi^(2^bb)
        float tv0 = Pc[0] * v0 + Pc[1] * v1 + Pc[2] * v2;
        float tv1 = Pc[3] * v0 + Pc[4] * v1 + Pc[5] * v2;
        float tv2 = Pc[6] * v0 + Pc[7] * v1 + Pc[8] * v2;
        const bool bit = (c >> bb) & 1;
        v0 = bit ? tv0 : v0; v1 = bit ? tv1 : v1; v2 = bit ? tv2 : v2;
    }
    mm3(Tm, Pc, Pc);                                         // Phi^64

    // ---- hoist wave-uniform constants to SGPRs ----
    float sPhi[9], sF64[9], sU[9];
#pragma unroll
    for (int e = 0; e < 9; ++e) {
        sPhi[e] = rfl(Phi[e]);
        sF64[e] = rfl(Tm[e]);
    }
    sU[0] = rfl(S2[3]); sU[1] = rfl(S2[4]); sU[2] = rfl(S2[5]);
    sU[3] = rfl(S3[3]); sU[4] = rfl(S3[4]); sU[5] = rfl(S3[5]);
    sU[6] = rfl(S4[3]); sU[7] = rfl(S4[4]); sU[8] = rfl(S4[5]);
    const float sD    = rfl(IC50p * Vc);          // denom scaled by Vc
    const float sWW1  = rfl(w1 * Imax);
    const float sWW2  = rfl(w2 * Imax);
    const float sWW3  = rfl(w3 * Imax);
    const float sWW4  = rfl(w4 * Imax);
    const float sB0   = rfl(beta0v);

    // scan weights (wave-uniform -> SGPR) + per-lane weights (VGPR)
    const float a1v = alpha, a2v = a1v * a1v, a4v = a2v * a2v;
    const float a8v = a4v * a4v, a16v = a8v * a8v, a32v = a16v * a16v;
    const float sA1 = rfl(a1v), sA2 = rfl(a2v), sA4 = rfl(a4v), sA8 = rfl(a8v);
    const float sA64  = rfl(a32v * a32v);        // alpha^64 (carry)
    const float sInvA = rfl(1.0f / alpha);       // exclusive-scan rebuild

    float pcaC = 1.0f;              // alpha^c (store weight)
    pcaC *= (c & 1)  ? a1v  : 1.0f;
    pcaC *= (c & 2)  ? a2v  : 1.0f;
    pcaC *= (c & 4)  ? a4v  : 1.0f;
    pcaC *= (c & 8)  ? a8v  : 1.0f;
    pcaC *= (c & 16) ? a16v : 1.0f;
    pcaC *= (c & 32) ? a32v : 1.0f;
    float w5 = a1v;                 // alpha^((c&15)+1), bridge rows 1&3
    w5 *= (c & 1) ? a1v : 1.0f;
    w5 *= (c & 2) ? a2v : 1.0f;
    w5 *= (c & 4) ? a4v : 1.0f;
    w5 *= (c & 8) ? a8v : 1.0f;
    float w6 = w5 * ((c & 16) ? a16v : 1.0f);   // alpha^((c&31)+1), rows 2&3

    // ---- doses (all 8 in regs; indices below are compile-time) ----
    const float4 dlo = ((const float4*)(dose_amt + subj * N_DOSES))[0];
    const float4 dhi = ((const float4*)(dose_amt + subj * N_DOSES))[1];
    const float ds[8] = { dlo.x, dlo.y, dlo.z, dlo.w, dhi.x, dhi.y, dhi.z, dhi.w };

    // ---- initial state: x = dose0 * Phi^c e1;  R carry = 16 ----
    float x0 = ds[0] * v0, x1d = ds[0] * v1, x2d = ds[0] * v2;
    float Rc = 16.0f;

    float4* orow = (float4*)out + (size_t)subj * (N_STEPS + 1);
    float4* op = orow + c;          // wave span [1024k, 1024(k+1)) of the row

    // beta(x): single-rcp form
#define BETA_FROM_X(bout)                                                  \
    do {                                                                   \
        float s1_ = x1d;                                                   \
        float s2_ = sU[0] * x0 + sU[1] * x1d + sU[2] * x2d;                \
        float s3_ = sU[3] * x0 + sU[4] * x1d + sU[5] * x2d;                \
        float s4_ = sU[6] * x0 + sU[7] * x1d + sU[8] * x2d;                \
        float d1_ = sD + s1_, d2_ = sD + s2_;                              \
        float d3_ = sD + s3_, d4_ = sD + s4_;                              \
        float n12_ = fmaf(sWW1 * s1_, d2_, (sWW2 * s2_) * d1_);            \
        float n34_ = fmaf(sWW3 * s3_, d4_, (sWW4 * s4_) * d3_);            \
        float d12_ = d1_ * d2_, d34_ = d3_ * d4_;                          \
        float num_ = fmaf(n12_, d34_, n34_ * d12_);                        \
        float rcp_ = __builtin_amdgcn_rcpf(d12_ * d34_);                   \
        bout = sB0 - num_ * rcp_;                                          \
    } while (0)

    float bta;
    BETA_FROM_X(bta);

#pragma unroll
    for (int k = 0; k < 32; ++k) {
        // weighted inclusive scan across the wave, pure DPP (no LDS):
        float I = bta;
        I = fmaf(sA1, DPPF(I, 0x111, 0xf), I);   // row_shr:1
        I = fmaf(sA2, DPPF(I, 0x112, 0xf), I);   // row_shr:2
        I = fmaf(sA4, DPPF(I, 0x114, 0xf), I);   // row_shr:4
        I = fmaf(sA8, DPPF(I, 0x118, 0xf), I);   // row_shr:8
        I = fmaf(w5, DPPF(I, 0x142, 0xa), I);    // row_bcast:15 -> rows 1,3
        I = fmaf(w6, DPPF(I, 0x143, 0xc), I);    // row_bcast:31 -> rows 2,3

        // exclusive scan: E_c = I_{c-1} = (I_c - beta_c)/alpha (exact 0 at c=0)
        float E = (I - bta) * sInvA;
        float Rst = fmaf(pcaC, Rc, E);           // R at index 64k+c

        // store state at output index 64k+c; at dose rounds lane 0 must
        // exclude the dose injected at this round boundary (exact subtract)
        float st0 = x0;
        if ((k & 3) == 0) { if (c == 0) st0 = x0 - ds[k >> 2]; }
        op[k * 64] = make_float4(st0, x1d, x2d, Rst);

        // carry R_{64(k+1)} = alpha^64 * Rc + I_63
        float I63 = __int_as_float(__builtin_amdgcn_readlane(__float_as_int(I), 63));
        Rc = fmaf(sA64, Rc, I63);

        if (k < 31) {
            // advance: x <- Phi^64 * x  (+ dose at segment boundary)
            float nx0 = sF64[0] * x0 + sF64[1] * x1d + sF64[2] * x2d;
            float nx1 = sF64[3] * x0 + sF64[4] * x1d + sF64[5] * x2d;
            float nx2 = sF64[6] * x0 + sF64[7] * x1d + sF64[8] * x2d;
            if ((k & 3) == 3) {
                const float dd = ds[(k >> 2) + 1];
                nx0 = fmaf(dd, v0, nx0);
                nx1 = fmaf(dd, v1, nx1);
                nx2 = fmaf(dd, v2, nx2);
            }
            x0 = nx0; x1d = nx1; x2d = nx2;
            BETA_FROM_X(bta);
        }
    }

    // final output index 2048 = Phi * x_{round31}; R = final carry
    {
        float xf0 = sPhi[0] * x0 + sPhi[1] * x1d + sPhi[2] * x2d;
        float xf1 = sPhi[3] * x0 + sPhi[4] * x1d + sPhi[5] * x2d;
        float xf2 = sPhi[6] * x0 + sPhi[7] * x1d + sPhi[8] * x2d;
        if (c == 63) orow[N_STEPS] = make_float4(xf0, xf1, xf2, Rc);
    }
#undef BETA_FROM_X
}

extern "C" void kernel_launch(void* const* d_in, const int* in_sizes, int n_in,
                              void* d_out, int out_size, void* d_ws, size_t ws_size,
                              hipStream_t stream) {
    const float* cov      = (const float*)d_in[0];
    const float* dose_int = (const float*)d_in[1];
    const float* Wm       = (const float*)d_in[2];
    const float* bvec     = (const float*)d_in[3];
    const float* dose_amt = (const float*)d_in[4];
    float* out = (float*)d_out;

    pkpd_tint_kernel<<<N_SUBJ / 4, 256, 0, stream>>>(cov, dose_int, Wm, bvec, dose_amt, out);
}